// Round 10
// baseline (112.747 us; speedup 1.0000x reference)
//
#include <hip/hip_runtime.h>
#include <math.h>

// Tacotron2 location-sensitive attention, fp32.
// B=64 T=2048 E=512 H=128 DL=1024 CC=32 K=31
// out = [context (B*E=32768), weights (B*T=131072)] fp32, concatenated.
// R10: producer/consumer wave specialization inside k1. Waves 0-1 compute
// energies per 64-t sub-tile (lane = t, fw via LDS broadcast); waves 2-3
// stream enc continuously, consuming sub-tiles as LDS flags are released
// (workgroup-scope atomics, CU-local -> none of R3's L2-fence cost).
// Sub-tile-granular online-max rescale (4x per block). 3 dispatches.

#define BB 64
#define TT 2048
#define EE 512
#define HH 128
#define DLL 1024
#define CCC 32
#define KK 31

// ws layout (in floats)
#define WS_FW   0        // fw[128][32] (col 31 = 0 pad)  -> 4096
#define WS_PL   4096     // pl[64][128]                   -> 8192
#define WS_EN   12288    // energies[64][2048]            -> 131072
#define WS_ST   143360   // stats[64][8][2] (m,s)         -> 1024
#define WS_PART 144384   // partials[64][8][512]          -> 262144

// ---------------------------------------------------------------------------
// k0: blocks 0..2047: one wave per (b,h) dot  pl[b][h] = lstm[b]·W_lstm[h]
//     block 2048: fw[h][k] = sum_c W_loc[h][c]*conv_w[c][k]
// ---------------------------------------------------------------------------
__global__ __launch_bounds__(256) void k0_prep(const float* __restrict__ lstm,
                                               const float* __restrict__ Wl,
                                               const float* __restrict__ cw,
                                               const float* __restrict__ Wloc,
                                               float* __restrict__ ws) {
  const int blk = blockIdx.x;
  const int tid = threadIdx.x;
  if (blk < 2048) {
    const int wave = tid >> 6, lane = tid & 63;
    const int wg = blk * 4 + wave;      // 0..8191
    const int b = wg >> 7, h = wg & 127;
    const float4* wr = (const float4*)(Wl + (size_t)h * DLL);
    const float4* lr = (const float4*)(lstm + (size_t)b * DLL);
    float s = 0.f;
#pragma unroll
    for (int m = 0; m < 4; ++m) {
      float4 a = wr[m * 64 + lane];
      float4 c = lr[m * 64 + lane];
      s += a.x * c.x + a.y * c.y + a.z * c.z + a.w * c.w;
    }
#pragma unroll
    for (int m = 1; m < 64; m <<= 1) s += __shfl_xor(s, m, 64);
    if (lane == 0) ws[WS_PL + b * HH + h] = s;
  } else {
    __shared__ __align__(16) float wl_s[HH * CCC];  // 4096
    __shared__ __align__(16) float cw_s[CCC * KK];  // 992
#pragma unroll
    for (int m = 0; m < 4; ++m)
      ((float4*)wl_s)[tid + 256 * m] = ((const float4*)Wloc)[tid + 256 * m];
    if (tid < 248) ((float4*)cw_s)[tid] = ((const float4*)cw)[tid];
    __syncthreads();
    const int h = tid >> 1;
    const int kbase = (tid & 1) * 16;
    const int kn = (tid & 1) ? 15 : 16;
    for (int kk = 0; kk < kn; ++kk) {
      const int k = kbase + kk;
      float s = 0.f;
#pragma unroll
      for (int c = 0; c < CCC; ++c) s += wl_s[h * CCC + c] * cw_s[c * KK + k];
      ws[WS_FW + h * 32 + k] = s;
    }
    if (tid & 1) ws[WS_FW + h * 32 + 31] = 0.f;  // pad
  }
}

// ---------------------------------------------------------------------------
// k1_fused: grid (8,64), 256 threads. Chunk = 256 t = 4 sub-tiles x 64 t.
// Producers (waves 0-1): wave w does sub-tiles {w, w+2}; lane = one t.
//   e[t] = sum_h We[h]*tanh(pl[h] + pe[t][h] + sum_k fw[h][k]*aw[t+k-15])
//   -> raw energy to ws, (m_i, s_i, exp(e-m_i)) to LDS, release flag.
// Consumers (waves 2-3): lane = one float4 col; per sub-tile: acquire flag,
//   rescale acc by sub-tile max growth, stream 64 enc rows. Partial write.
// ---------------------------------------------------------------------------
__global__ __launch_bounds__(256) void k1_fused(const float* __restrict__ pe,
                                                const float* __restrict__ aw,
                                                const float* __restrict__ We,
                                                const float* __restrict__ enc,
                                                float* __restrict__ ws) {
  const int b = blockIdx.y;
  const int chunk = blockIdx.x;      // 0..7
  const int t0 = chunk * 256;
  const int tid = threadIdx.x;
  const int wave = tid >> 6, lane = tid & 63;

  __shared__ __align__(16) float fw_s[HH * 32];  // 16 KB
  __shared__ __align__(16) float aw_s[288];      // halo window
  __shared__ float pl_s[128];
  __shared__ float we_s[128];
  __shared__ float w_s[256];                     // exp(e - m_sub)
  __shared__ float m_arr[4], s_arr[4];
  __shared__ int flag_s[4];

  // staging (all waves)
  {
    const float4* src = (const float4*)(ws + WS_FW);
    float4* dst = (float4*)fw_s;
#pragma unroll
    for (int i = 0; i < 4; ++i) dst[tid + 256 * i] = src[tid + 256 * i];
  }
  {
    int tg = t0 - 16 + tid;
    aw_s[tid] = (tg >= 0 && tg < TT) ? aw[b * TT + tg] : 0.f;
    if (tid < 32) {
      tg = t0 + 240 + tid;
      aw_s[256 + tid] = (tg >= 0 && tg < TT) ? aw[b * TT + tg] : 0.f;
    }
  }
  if (tid < 128) {
    pl_s[tid] = ws[WS_PL + b * HH + tid];
    we_s[tid] = We[tid];
  }
  if (tid < 4) flag_s[tid] = 0;
  __syncthreads();

  if (wave < 2) {
    // ---------------- producers ----------------
    for (int si = 0; si < 2; ++si) {
      const int sub = si * 2 + wave;     // wave0: 0,2  wave1: 1,3
      const int lt = sub * 64 + lane;    // local t 0..255
      float wreg[32];
#pragma unroll
      for (int k = 0; k < 32; ++k) wreg[k] = aw_s[lt + 1 + k];
      const float4* pr4 = (const float4*)(pe + ((size_t)b * TT + t0 + lt) * HH);
      float e_acc = 0.f;
#pragma unroll 1
      for (int h0 = 0; h0 < 128; h0 += 16) {
        float4 ptv[4];
#pragma unroll
        for (int i = 0; i < 4; ++i) ptv[i] = pr4[(h0 >> 2) + i];
        float pts[16];
#pragma unroll
        for (int i = 0; i < 4; ++i) {
          pts[4 * i + 0] = ptv[i].x; pts[4 * i + 1] = ptv[i].y;
          pts[4 * i + 2] = ptv[i].z; pts[4 * i + 3] = ptv[i].w;
        }
#pragma unroll 2
        for (int hh = 0; hh < 16; ++hh) {
          const int h = h0 + hh;
          const float4* fr = (const float4*)&fw_s[h * 32];  // broadcast
          float a0 = pl_s[h] + pts[hh];
          float a1 = 0.f;
#pragma unroll
          for (int q = 0; q < 8; ++q) {
            const float4 f = fr[q];
            a0 = fmaf(f.x, wreg[4 * q + 0], a0);
            a1 = fmaf(f.y, wreg[4 * q + 1], a1);
            a0 = fmaf(f.z, wreg[4 * q + 2], a0);
            a1 = fmaf(f.w, wreg[4 * q + 3], a1);  // q=7: f.w = 0 pad
          }
          const float x = a0 + a1;
          const float th = 1.f - 2.f / (__expf(2.f * x) + 1.f);
          e_acc = fmaf(we_s[h], th, e_acc);
        }
      }
      ws[WS_EN + b * TT + t0 + lt] = e_acc;  // coalesced 64-wide

      float m = e_acc;
#pragma unroll
      for (int s = 1; s < 64; s <<= 1) m = fmaxf(m, __shfl_xor(m, s, 64));
      float p = __expf(e_acc - m);
#pragma unroll
      for (int s = 1; s < 64; s <<= 1) p += __shfl_xor(p, s, 64);
      w_s[lt] = __expf(e_acc - m);
      if (lane == 0) { m_arr[sub] = m; s_arr[sub] = p; }
      __hip_atomic_store(&flag_s[sub], 1, __ATOMIC_RELEASE,
                         __HIP_MEMORY_SCOPE_WORKGROUP);
    }
  } else {
    // ---------------- consumers ----------------
    const int col = tid & 127;  // float4 column 0..127
    const float4* enc4 = (const float4*)(enc + ((size_t)b * TT + t0) * EE);
    float4 a0 = {0.f, 0.f, 0.f, 0.f}, a1 = {0.f, 0.f, 0.f, 0.f};
    float mrun = -3.4e38f;
#pragma unroll 1
    for (int sub = 0; sub < 4; ++sub) {
      while (!__hip_atomic_load(&flag_s[sub], __ATOMIC_ACQUIRE,
                                __HIP_MEMORY_SCOPE_WORKGROUP))
        __builtin_amdgcn_s_sleep(2);
      const float mi = m_arr[sub];
      const float mnew = fmaxf(mrun, mi);
      const float so = __expf(mrun - mnew);  // 0 on first sub
      const float sc = __expf(mi - mnew);
      a0.x *= so; a0.y *= so; a0.z *= so; a0.w *= so;
      a1.x *= so; a1.y *= so; a1.z *= so; a1.w *= so;
      const float* wp = &w_s[sub * 64];
#pragma unroll 8
      for (int t = 0; t < 64; ++t) {
        const float w = wp[t] * sc;
        const float4 v = enc4[(size_t)(sub * 64 + t) * 128 + col];
        if (t & 1) {
          a1.x = fmaf(w, v.x, a1.x); a1.y = fmaf(w, v.y, a1.y);
          a1.z = fmaf(w, v.z, a1.z); a1.w = fmaf(w, v.w, a1.w);
        } else {
          a0.x = fmaf(w, v.x, a0.x); a0.y = fmaf(w, v.y, a0.y);
          a0.z = fmaf(w, v.z, a0.z); a0.w = fmaf(w, v.w, a0.w);
        }
      }
      mrun = mnew;
    }
    a0.x += a1.x; a0.y += a1.y; a0.z += a1.z; a0.w += a1.w;
    // acc is scaled to block max (mrun = max of all sub maxes)
    ((float4*)(ws + WS_PART))[(size_t)(b * 8 + chunk) * 128 + col] = a0;
  }

  __syncthreads();
  if (tid == 0) {
    const float mb = fmaxf(fmaxf(m_arr[0], m_arr[1]), fmaxf(m_arr[2], m_arr[3]));
    float sb = 0.f;
#pragma unroll
    for (int c = 0; c < 4; ++c) sb += s_arr[c] * __expf(m_arr[c] - mb);
    float* st = ws + WS_ST + (b * 8 + chunk) * 2;
    st[0] = mb;
    st[1] = sb;
  }
}

// ---------------------------------------------------------------------------
// k2_combine: per b: global (m, S) from 8 chunk stats; weights from raw
// energies; ctx = sum_c exp(m_c - m) * partial_c / S (fixed order). 64 blocks.
// ---------------------------------------------------------------------------
__global__ __launch_bounds__(256) void k2_combine(const float* __restrict__ ws,
                                                  float* __restrict__ wts,
                                                  float* __restrict__ ctx) {
  const int b = blockIdx.x;
  const int tid = threadIdx.x;

  const float* st = ws + WS_ST + b * 16;
  float mb = -3.4e38f;
#pragma unroll
  for (int c = 0; c < 8; ++c) mb = fmaxf(mb, st[2 * c]);
  float S = 0.f;
#pragma unroll
  for (int c = 0; c < 8; ++c) S += st[2 * c + 1] * __expf(st[2 * c] - mb);
  const float inv = 1.f / S;

  __shared__ float esc[8];
  if (tid < 8) esc[tid] = __expf(st[2 * tid] - mb) * inv;
  __syncthreads();

  // weights: 2048 per b
  const float4* en4 = (const float4*)(ws + WS_EN + (size_t)b * TT);
  float4* w4 = (float4*)(wts + (size_t)b * TT);
#pragma unroll
  for (int j = 0; j < 2; ++j) {
    const float4 e = en4[tid * 2 + j];
    float4 w;
    w.x = __expf(e.x - mb) * inv;
    w.y = __expf(e.y - mb) * inv;
    w.z = __expf(e.z - mb) * inv;
    w.w = __expf(e.w - mb) * inv;
    w4[tid * 2 + j] = w;
  }

  // ctx: 512 per b; thread owns float2 column
  const float2* p2 = (const float2*)(ws + WS_PART) + (size_t)b * 8 * 256 + tid;
  float2 s = {0.f, 0.f};
#pragma unroll
  for (int c = 0; c < 8; ++c) {
    const float2 v = p2[c * 256];
    s.x = fmaf(esc[c], v.x, s.x);
    s.y = fmaf(esc[c], v.y, s.y);
  }
  ((float2*)ctx)[b * 256 + tid] = s;
}

// ---------------------------------------------------------------------------
extern "C" void kernel_launch(void* const* d_in, const int* in_sizes, int n_in,
                              void* d_out, int out_size, void* d_ws, size_t ws_size,
                              hipStream_t stream) {
  const float* enc  = (const float*)d_in[0];  // [B,T,E]
  const float* pe   = (const float*)d_in[1];  // [B,T,H]
  const float* lstm = (const float*)d_in[2];  // [B,1,DL]
  const float* awc  = (const float*)d_in[3];  // [B,T]
  const float* Wl   = (const float*)d_in[4];  // [H,DL]
  const float* cw   = (const float*)d_in[5];  // [CC,1,K]
  const float* Wloc = (const float*)d_in[6];  // [H,CC]
  const float* We   = (const float*)d_in[7];  // [1,H]

  float* out = (float*)d_out;
  float* ctx = out;            // [B,E]
  float* wts = out + BB * EE;  // [B,T]
  float* ws = (float*)d_ws;

  k0_prep<<<2049, 256, 0, stream>>>(lstm, Wl, cw, Wloc, ws);
  k1_fused<<<dim3(8, BB), 256, 0, stream>>>(pe, awc, We, enc, ws);
  k2_combine<<<BB, 256, 0, stream>>>(ws, wts, ctx);
}

// Round 11
// 86.975 us; speedup vs baseline: 1.2963x; 1.2963x over previous
//
#include <hip/hip_runtime.h>
#include <math.h>

// Tacotron2 location-sensitive attention, fp32.
// B=64 T=2048 E=512 H=128 DL=1024 CC=32 K=31
// out = [context (B*E=32768), weights (B*T=131072)] fp32, concatenated.
// R11: balanced producer/consumer. 512-thr blocks, grid (8,64) = 2 blocks/CU.
// Waves 0-3 produce energies (one 64-t sub-tile each; lane=t; fw via LDS
// broadcast) -> full 2048 producer waves = R9 phase-A width. Waves 4-7
// consume: stream enc concurrently as LDS flags release, online rescale
// per sub-tile (R10-verified numerics). 3 dispatches, no global fences.

#define BB 64
#define TT 2048
#define EE 512
#define HH 128
#define DLL 1024
#define CCC 32
#define KK 31

// ws layout (in floats)
#define WS_FW   0        // fw[128][32] (col 31 = 0 pad)  -> 4096
#define WS_PL   4096     // pl[64][128]                   -> 8192
#define WS_EN   12288    // energies[64][2048]            -> 131072
#define WS_ST   143360   // stats[64][8][2] (m,s)         -> 1024
#define WS_PART 144384   // partials[64][8][512]          -> 262144

// ---------------------------------------------------------------------------
// k0: blocks 0..2047: one wave per (b,h) dot  pl[b][h] = lstm[b]·W_lstm[h]
//     block 2048: fw[h][k] = sum_c W_loc[h][c]*conv_w[c][k]
// ---------------------------------------------------------------------------
__global__ __launch_bounds__(256) void k0_prep(const float* __restrict__ lstm,
                                               const float* __restrict__ Wl,
                                               const float* __restrict__ cw,
                                               const float* __restrict__ Wloc,
                                               float* __restrict__ ws) {
  const int blk = blockIdx.x;
  const int tid = threadIdx.x;
  if (blk < 2048) {
    const int wave = tid >> 6, lane = tid & 63;
    const int wg = blk * 4 + wave;      // 0..8191
    const int b = wg >> 7, h = wg & 127;
    const float4* wr = (const float4*)(Wl + (size_t)h * DLL);
    const float4* lr = (const float4*)(lstm + (size_t)b * DLL);
    float s = 0.f;
#pragma unroll
    for (int m = 0; m < 4; ++m) {
      float4 a = wr[m * 64 + lane];
      float4 c = lr[m * 64 + lane];
      s += a.x * c.x + a.y * c.y + a.z * c.z + a.w * c.w;
    }
#pragma unroll
    for (int m = 1; m < 64; m <<= 1) s += __shfl_xor(s, m, 64);
    if (lane == 0) ws[WS_PL + b * HH + h] = s;
  } else {
    __shared__ __align__(16) float wl_s[HH * CCC];  // 4096
    __shared__ __align__(16) float cw_s[CCC * KK];  // 992
#pragma unroll
    for (int m = 0; m < 4; ++m)
      ((float4*)wl_s)[tid + 256 * m] = ((const float4*)Wloc)[tid + 256 * m];
    if (tid < 248) ((float4*)cw_s)[tid] = ((const float4*)cw)[tid];
    __syncthreads();
    const int h = tid >> 1;
    const int kbase = (tid & 1) * 16;
    const int kn = (tid & 1) ? 15 : 16;
    for (int kk = 0; kk < kn; ++kk) {
      const int k = kbase + kk;
      float s = 0.f;
#pragma unroll
      for (int c = 0; c < CCC; ++c) s += wl_s[h * CCC + c] * cw_s[c * KK + k];
      ws[WS_FW + h * 32 + k] = s;
    }
    if (tid & 1) ws[WS_FW + h * 32 + 31] = 0.f;  // pad
  }
}

// ---------------------------------------------------------------------------
// k1_fused: grid (8,64), 512 threads. Chunk = 256 t = 4 sub-tiles x 64 t.
// Producers (waves 0-3): wave w -> sub-tile w, lane = one t.
// Consumers (waves 4-7): cid = tid-256; float4 col c4 = cid&127, parity
// tp = cid>>7 (wave-uniform); stream rows t%2==tp of each sub as released.
// ---------------------------------------------------------------------------
__global__ __launch_bounds__(512, 4) void k1_fused(const float* __restrict__ pe,
                                                   const float* __restrict__ aw,
                                                   const float* __restrict__ We,
                                                   const float* __restrict__ enc,
                                                   float* __restrict__ ws) {
  const int b = blockIdx.y;
  const int chunk = blockIdx.x;      // 0..7
  const int t0 = chunk * 256;
  const int tid = threadIdx.x;
  const int wave = tid >> 6, lane = tid & 63;

  __shared__ __align__(16) float fw_s[HH * 32];   // 16 KB
  __shared__ __align__(16) float aw_s[288];       // halo window
  __shared__ float pl_s[128];
  __shared__ float we_s[128];
  __shared__ float w_s[256];                      // exp(e - m_sub)
  __shared__ __align__(16) float4 acc_s[128];     // consumer parity combine
  __shared__ float m_arr[4], s_arr[4];
  __shared__ int flag_s[4];

  // cooperative staging (all 512 threads)
  {
    const float4* src = (const float4*)(ws + WS_FW);
    float4* dst = (float4*)fw_s;
    dst[tid] = src[tid];
    dst[tid + 512] = src[tid + 512];
  }
  if (tid < 288) {
    const int tg = t0 - 16 + tid;
    aw_s[tid] = (tg >= 0 && tg < TT) ? aw[b * TT + tg] : 0.f;
  }
  if (tid < 128) {
    pl_s[tid] = ws[WS_PL + b * HH + tid];
    we_s[tid] = We[tid];
  }
  if (tid < 4) flag_s[tid] = 0;
  __syncthreads();

  if (wave < 4) {
    // ---------------- producers: wave w -> sub-tile w ----------------
    const int lt = wave * 64 + lane;   // local t 0..255
    float wreg[32];
#pragma unroll
    for (int k = 0; k < 32; ++k) wreg[k] = aw_s[lt + 1 + k];
    const float4* pr4 = (const float4*)(pe + ((size_t)b * TT + t0 + lt) * HH);
    float e_acc = 0.f;
#pragma unroll 1
    for (int h0 = 0; h0 < 128; h0 += 16) {
      float4 ptv[4];
#pragma unroll
      for (int i = 0; i < 4; ++i) ptv[i] = pr4[(h0 >> 2) + i];
      float pts[16];
#pragma unroll
      for (int i = 0; i < 4; ++i) {
        pts[4 * i + 0] = ptv[i].x; pts[4 * i + 1] = ptv[i].y;
        pts[4 * i + 2] = ptv[i].z; pts[4 * i + 3] = ptv[i].w;
      }
#pragma unroll 2
      for (int hh = 0; hh < 16; ++hh) {
        const int h = h0 + hh;
        const float4* fr = (const float4*)&fw_s[h * 32];  // broadcast
        float a0 = pl_s[h] + pts[hh];
        float a1 = 0.f;
#pragma unroll
        for (int q = 0; q < 8; ++q) {
          const float4 f = fr[q];
          a0 = fmaf(f.x, wreg[4 * q + 0], a0);
          a1 = fmaf(f.y, wreg[4 * q + 1], a1);
          a0 = fmaf(f.z, wreg[4 * q + 2], a0);
          a1 = fmaf(f.w, wreg[4 * q + 3], a1);  // q=7: f.w = 0 pad
        }
        const float x = a0 + a1;
        const float th = 1.f - 2.f / (__expf(2.f * x) + 1.f);
        e_acc = fmaf(we_s[h], th, e_acc);
      }
    }
    ws[WS_EN + b * TT + t0 + lt] = e_acc;  // coalesced 64-wide

    float m = e_acc;
#pragma unroll
    for (int s = 1; s < 64; s <<= 1) m = fmaxf(m, __shfl_xor(m, s, 64));
    float p = __expf(e_acc - m);
#pragma unroll
    for (int s = 1; s < 64; s <<= 1) p += __shfl_xor(p, s, 64);
    w_s[lt] = __expf(e_acc - m);
    if (lane == 0) { m_arr[wave] = m; s_arr[wave] = p; }
    __hip_atomic_store(&flag_s[wave], 1, __ATOMIC_RELEASE,
                       __HIP_MEMORY_SCOPE_WORKGROUP);
  } else {
    // ---------------- consumers ----------------
    const int cid = tid - 256;     // 0..255
    const int c4 = cid & 127;      // float4 column
    const int tp = cid >> 7;       // parity (wave-uniform)
    const float4* enc4 = (const float4*)(enc + ((size_t)b * TT + t0) * EE);
    float4 a0 = {0.f, 0.f, 0.f, 0.f}, a1 = {0.f, 0.f, 0.f, 0.f};
    float mrun = -3.4e38f;
#pragma unroll 1
    for (int sub = 0; sub < 4; ++sub) {
      while (!__hip_atomic_load(&flag_s[sub], __ATOMIC_ACQUIRE,
                                __HIP_MEMORY_SCOPE_WORKGROUP))
        __builtin_amdgcn_s_sleep(2);
      const float mi = m_arr[sub];
      const float mnew = fmaxf(mrun, mi);
      const float so = __expf(mrun - mnew);  // 0 on first sub
      const float sc = __expf(mi - mnew);
      a0.x *= so; a0.y *= so; a0.z *= so; a0.w *= so;
      a1.x *= so; a1.y *= so; a1.z *= so; a1.w *= so;
      const float* wp = &w_s[sub * 64];
#pragma unroll 8
      for (int i = 0; i < 32; ++i) {
        const int t = 2 * i + tp;
        const float w = wp[t] * sc;
        const float4 v = enc4[(size_t)(sub * 64 + t) * 128 + c4];
        if (i & 1) {
          a1.x = fmaf(w, v.x, a1.x); a1.y = fmaf(w, v.y, a1.y);
          a1.z = fmaf(w, v.z, a1.z); a1.w = fmaf(w, v.w, a1.w);
        } else {
          a0.x = fmaf(w, v.x, a0.x); a0.y = fmaf(w, v.y, a0.y);
          a0.z = fmaf(w, v.z, a0.z); a0.w = fmaf(w, v.w, a0.w);
        }
      }
      mrun = mnew;
    }
    a0.x += a1.x; a0.y += a1.y; a0.z += a1.z; a0.w += a1.w;
    if (tp == 1) acc_s[c4] = a0;      // acc scaled to block max already
    else {
      // stash own acc in registers; combine after barrier
      acc_s[c4].x = acc_s[c4].x;      // no-op placeholder (avoid branch WAR)
    }
    // carry a0 to after-barrier via registers (tp==0 path)
    __syncthreads();
    if (tp == 0) {
      const float4 o = acc_s[c4];
      a0.x += o.x; a0.y += o.y; a0.z += o.z; a0.w += o.w;
      ((float4*)(ws + WS_PART))[(size_t)(b * 8 + chunk) * 128 + c4] = a0;
    }
    // stats
    if (cid == 0) {
      const float mb = fmaxf(fmaxf(m_arr[0], m_arr[1]),
                             fmaxf(m_arr[2], m_arr[3]));
      float sb = 0.f;
#pragma unroll
      for (int c = 0; c < 4; ++c) sb += s_arr[c] * __expf(m_arr[c] - mb);
      float* st = ws + WS_ST + (b * 8 + chunk) * 2;
      st[0] = mb;
      st[1] = sb;
    }
    return;
  }
  __syncthreads();  // producers join the consumer barrier
}

// ---------------------------------------------------------------------------
// k2_combine: per b: global (m, S) from 8 chunk stats; weights from raw
// energies; ctx = sum_c exp(m_c - m) * partial_c / S (fixed order). 64 blocks.
// ---------------------------------------------------------------------------
__global__ __launch_bounds__(256) void k2_combine(const float* __restrict__ ws,
                                                  float* __restrict__ wts,
                                                  float* __restrict__ ctx) {
  const int b = blockIdx.x;
  const int tid = threadIdx.x;

  const float* st = ws + WS_ST + b * 16;
  float mb = -3.4e38f;
#pragma unroll
  for (int c = 0; c < 8; ++c) mb = fmaxf(mb, st[2 * c]);
  float S = 0.f;
#pragma unroll
  for (int c = 0; c < 8; ++c) S += st[2 * c + 1] * __expf(st[2 * c] - mb);
  const float inv = 1.f / S;

  __shared__ float esc[8];
  if (tid < 8) esc[tid] = __expf(st[2 * tid] - mb) * inv;
  __syncthreads();

  // weights: 2048 per b
  const float4* en4 = (const float4*)(ws + WS_EN + (size_t)b * TT);
  float4* w4 = (float4*)(wts + (size_t)b * TT);
#pragma unroll
  for (int j = 0; j < 2; ++j) {
    const float4 e = en4[tid * 2 + j];
    float4 w;
    w.x = __expf(e.x - mb) * inv;
    w.y = __expf(e.y - mb) * inv;
    w.z = __expf(e.z - mb) * inv;
    w.w = __expf(e.w - mb) * inv;
    w4[tid * 2 + j] = w;
  }

  // ctx: 512 per b; thread owns float2 column
  const float2* p2 = (const float2*)(ws + WS_PART) + (size_t)b * 8 * 256 + tid;
  float2 s = {0.f, 0.f};
#pragma unroll
  for (int c = 0; c < 8; ++c) {
    const float2 v = p2[c * 256];
    s.x = fmaf(esc[c], v.x, s.x);
    s.y = fmaf(esc[c], v.y, s.y);
  }
  ((float2*)ctx)[b * 256 + tid] = s;
}

// ---------------------------------------------------------------------------
extern "C" void kernel_launch(void* const* d_in, const int* in_sizes, int n_in,
                              void* d_out, int out_size, void* d_ws, size_t ws_size,
                              hipStream_t stream) {
  const float* enc  = (const float*)d_in[0];  // [B,T,E]
  const float* pe   = (const float*)d_in[1];  // [B,T,H]
  const float* lstm = (const float*)d_in[2];  // [B,1,DL]
  const float* awc  = (const float*)d_in[3];  // [B,T]
  const float* Wl   = (const float*)d_in[4];  // [H,DL]
  const float* cw   = (const float*)d_in[5];  // [CC,1,K]
  const float* Wloc = (const float*)d_in[6];  // [H,CC]
  const float* We   = (const float*)d_in[7];  // [1,H]

  float* out = (float*)d_out;
  float* ctx = out;            // [B,E]
  float* wts = out + BB * EE;  // [B,T]
  float* ws = (float*)d_ws;

  k0_prep<<<2049, 256, 0, stream>>>(lstm, Wl, cw, Wloc, ws);
  k1_fused<<<dim3(8, BB), 512, 0, stream>>>(pe, awc, We, enc, ws);
  k2_combine<<<BB, 256, 0, stream>>>(ws, wts, ctx);
}

// Round 12
// 78.291 us; speedup vs baseline: 1.4401x; 1.1109x over previous
//
#include <hip/hip_runtime.h>
#include <math.h>

// Tacotron2 location-sensitive attention, fp32.
// B=64 T=2048 E=512 H=128 DL=1024 CC=32 K=31
// out = [context (B*E=32768), weights (B*T=131072)] fp32, concatenated.
// R12: staggered cooperative producers. Producer waves 0-3 split the H
// dimension (32 h each) and sweep the 4 sub-tiles IN ORDER, so sub 0's
// flag releases at ~T_A/4 and consumers (waves 4-7) stream enc
// continuously from then on. Last-arriver wave (LDS counter) combines
// partials (fixed order -> deterministic). 3 dispatches, no L2 fences.

#define BB 64
#define TT 2048
#define EE 512
#define HH 128
#define DLL 1024
#define CCC 32
#define KK 31

// ws layout (in floats)
#define WS_FW   0        // fw[128][32] (col 31 = 0 pad)  -> 4096
#define WS_PL   4096     // pl[64][128]                   -> 8192
#define WS_EN   12288    // energies[64][2048]            -> 131072
#define WS_ST   143360   // stats[64][8][2] (m,s)         -> 1024
#define WS_PART 144384   // partials[64][8][512]          -> 262144

// ---------------------------------------------------------------------------
// k0: blocks 0..2047: one wave per (b,h) dot  pl[b][h] = lstm[b]·W_lstm[h]
//     block 2048: fw[h][k] = sum_c W_loc[h][c]*conv_w[c][k]
// ---------------------------------------------------------------------------
__global__ __launch_bounds__(256) void k0_prep(const float* __restrict__ lstm,
                                               const float* __restrict__ Wl,
                                               const float* __restrict__ cw,
                                               const float* __restrict__ Wloc,
                                               float* __restrict__ ws) {
  const int blk = blockIdx.x;
  const int tid = threadIdx.x;
  if (blk < 2048) {
    const int wave = tid >> 6, lane = tid & 63;
    const int wg = blk * 4 + wave;      // 0..8191
    const int b = wg >> 7, h = wg & 127;
    const float4* wr = (const float4*)(Wl + (size_t)h * DLL);
    const float4* lr = (const float4*)(lstm + (size_t)b * DLL);
    float s = 0.f;
#pragma unroll
    for (int m = 0; m < 4; ++m) {
      float4 a = wr[m * 64 + lane];
      float4 c = lr[m * 64 + lane];
      s += a.x * c.x + a.y * c.y + a.z * c.z + a.w * c.w;
    }
#pragma unroll
    for (int m = 1; m < 64; m <<= 1) s += __shfl_xor(s, m, 64);
    if (lane == 0) ws[WS_PL + b * HH + h] = s;
  } else {
    __shared__ __align__(16) float wl_s[HH * CCC];  // 4096
    __shared__ __align__(16) float cw_s[CCC * KK];  // 992
#pragma unroll
    for (int m = 0; m < 4; ++m)
      ((float4*)wl_s)[tid + 256 * m] = ((const float4*)Wloc)[tid + 256 * m];
    if (tid < 248) ((float4*)cw_s)[tid] = ((const float4*)cw)[tid];
    __syncthreads();
    const int h = tid >> 1;
    const int kbase = (tid & 1) * 16;
    const int kn = (tid & 1) ? 15 : 16;
    for (int kk = 0; kk < kn; ++kk) {
      const int k = kbase + kk;
      float s = 0.f;
#pragma unroll
      for (int c = 0; c < CCC; ++c) s += wl_s[h * CCC + c] * cw_s[c * KK + k];
      ws[WS_FW + h * 32 + k] = s;
    }
    if (tid & 1) ws[WS_FW + h * 32 + 31] = 0.f;  // pad
  }
}

// ---------------------------------------------------------------------------
// k1_fused: grid (8,64), 512 threads. Chunk = 256 t = 4 sub-tiles x 64 t.
// Producers (waves 0-3): wave w computes partial energies over h in
// [32w,32w+32) for EVERY sub-tile, in sub order; LDS pp[sub][w][t];
// last-arriver combines + releases flag. Consumers (waves 4-7): per sub,
// acquire flag, online rescale, stream 64 enc rows (col,parity layout).
// ---------------------------------------------------------------------------
__global__ __launch_bounds__(512, 4) void k1_fused(const float* __restrict__ pe,
                                                   const float* __restrict__ aw,
                                                   const float* __restrict__ We,
                                                   const float* __restrict__ enc,
                                                   float* __restrict__ ws) {
  const int b = blockIdx.y;
  const int chunk = blockIdx.x;      // 0..7
  const int t0 = chunk * 256;
  const int tid = threadIdx.x;
  const int wave = tid >> 6, lane = tid & 63;

  __shared__ __align__(16) float fw_s[HH * 32];   // 16 KB
  __shared__ __align__(16) float aw_s[288];       // halo window
  __shared__ float pl_s[128];
  __shared__ float we_s[128];
  __shared__ __align__(16) float pp[4][4][64];    // partial e [sub][wave][t]
  __shared__ float w_s[256];                      // exp(e - m_sub)
  __shared__ __align__(16) float4 acc_s[128];     // consumer parity combine
  __shared__ float m_arr[4], s_arr[4];
  __shared__ int flag_s[4], cnt_s[4];

  // cooperative staging (all 512 threads)
  {
    const float4* src = (const float4*)(ws + WS_FW);
    float4* dst = (float4*)fw_s;
    dst[tid] = src[tid];
    dst[tid + 512] = src[tid + 512];
  }
  if (tid < 288) {
    const int tg = t0 - 16 + tid;
    aw_s[tid] = (tg >= 0 && tg < TT) ? aw[b * TT + tg] : 0.f;
  }
  if (tid < 128) {
    pl_s[tid] = ws[WS_PL + b * HH + tid];
    we_s[tid] = We[tid];
  }
  if (tid < 4) { flag_s[tid] = 0; cnt_s[tid] = 0; }
  __syncthreads();

  if (wave < 4) {
    // ------- producers: wave w -> h in [32w, 32w+32), all subs in order ----
    const int hbase = wave * 32;
#pragma unroll 1
    for (int sub = 0; sub < 4; ++sub) {
      const int lt = sub * 64 + lane;   // local t
      float wreg[32];
#pragma unroll
      for (int k = 0; k < 32; ++k) wreg[k] = aw_s[lt + 1 + k];
      // pe row segment: 8 float4 = 32 h starting at hbase
      const float4* pr4 = (const float4*)(pe + ((size_t)b * TT + t0 + lt) * HH) +
                          (hbase >> 2);
      float4 ptv[8];
#pragma unroll
      for (int i = 0; i < 8; ++i) ptv[i] = pr4[i];
      float pts[32];
#pragma unroll
      for (int i = 0; i < 8; ++i) {
        pts[4 * i + 0] = ptv[i].x; pts[4 * i + 1] = ptv[i].y;
        pts[4 * i + 2] = ptv[i].z; pts[4 * i + 3] = ptv[i].w;
      }
      float partial = 0.f;
#pragma unroll 2
      for (int hh = 0; hh < 32; ++hh) {
        const int h = hbase + hh;
        const float4* fr = (const float4*)&fw_s[h * 32];  // broadcast
        float a0 = pl_s[h] + pts[hh];
        float a1 = 0.f;
#pragma unroll
        for (int q = 0; q < 8; ++q) {
          const float4 f = fr[q];
          a0 = fmaf(f.x, wreg[4 * q + 0], a0);
          a1 = fmaf(f.y, wreg[4 * q + 1], a1);
          a0 = fmaf(f.z, wreg[4 * q + 2], a0);
          a1 = fmaf(f.w, wreg[4 * q + 3], a1);  // q=7: f.w = 0 pad
        }
        const float x = a0 + a1;
        const float th = 1.f - 2.f / (__expf(2.f * x) + 1.f);
        partial = fmaf(we_s[h], th, partial);
      }
      pp[sub][wave][lane] = partial;

      int old = 0;
      if (lane == 0)
        old = __hip_atomic_fetch_add(&cnt_s[sub], 1, __ATOMIC_ACQ_REL,
                                     __HIP_MEMORY_SCOPE_WORKGROUP);
      old = __shfl(old, 0, 64);
      if (old == 3) {
        // last arriver: fixed-order combine (deterministic result)
        const float e = pp[sub][0][lane] + pp[sub][1][lane] +
                        pp[sub][2][lane] + pp[sub][3][lane];
        ws[WS_EN + b * TT + t0 + lt] = e;  // coalesced 64-wide
        float m = e;
#pragma unroll
        for (int s = 1; s < 64; s <<= 1) m = fmaxf(m, __shfl_xor(m, s, 64));
        float p = __expf(e - m);
#pragma unroll
        for (int s = 1; s < 64; s <<= 1) p += __shfl_xor(p, s, 64);
        w_s[lt] = __expf(e - m);
        if (lane == 0) { m_arr[sub] = m; s_arr[sub] = p; }
        __hip_atomic_store(&flag_s[sub], 1, __ATOMIC_RELEASE,
                           __HIP_MEMORY_SCOPE_WORKGROUP);
      }
    }
    __syncthreads();  // join consumers' barrier
  } else {
    // ---------------- consumers ----------------
    const int cid = tid - 256;     // 0..255
    const int c4 = cid & 127;      // float4 column
    const int tp = cid >> 7;       // parity (wave-uniform)
    const float4* enc4 = (const float4*)(enc + ((size_t)b * TT + t0) * EE);
    float4 a0 = {0.f, 0.f, 0.f, 0.f}, a1 = {0.f, 0.f, 0.f, 0.f};
    float mrun = -3.4e38f;
#pragma unroll 1
    for (int sub = 0; sub < 4; ++sub) {
      while (!__hip_atomic_load(&flag_s[sub], __ATOMIC_ACQUIRE,
                                __HIP_MEMORY_SCOPE_WORKGROUP))
        __builtin_amdgcn_s_sleep(2);
      const float mi = m_arr[sub];
      const float mnew = fmaxf(mrun, mi);
      const float so = __expf(mrun - mnew);  // 0 on first sub
      const float sc = __expf(mi - mnew);
      a0.x *= so; a0.y *= so; a0.z *= so; a0.w *= so;
      a1.x *= so; a1.y *= so; a1.z *= so; a1.w *= so;
      const float* wp = &w_s[sub * 64];
#pragma unroll 8
      for (int i = 0; i < 32; ++i) {
        const int t = 2 * i + tp;
        const float w = wp[t] * sc;
        const float4 v = enc4[(size_t)(sub * 64 + t) * 128 + c4];
        if (i & 1) {
          a1.x = fmaf(w, v.x, a1.x); a1.y = fmaf(w, v.y, a1.y);
          a1.z = fmaf(w, v.z, a1.z); a1.w = fmaf(w, v.w, a1.w);
        } else {
          a0.x = fmaf(w, v.x, a0.x); a0.y = fmaf(w, v.y, a0.y);
          a0.z = fmaf(w, v.z, a0.z); a0.w = fmaf(w, v.w, a0.w);
        }
      }
      mrun = mnew;
    }
    a0.x += a1.x; a0.y += a1.y; a0.z += a1.z; a0.w += a1.w;
    if (tp == 1) acc_s[c4] = a0;      // acc scaled to block max already
    __syncthreads();
    if (tp == 0) {
      const float4 o = acc_s[c4];
      a0.x += o.x; a0.y += o.y; a0.z += o.z; a0.w += o.w;
      ((float4*)(ws + WS_PART))[(size_t)(b * 8 + chunk) * 128 + c4] = a0;
    }
    if (cid == 0) {
      const float mb = fmaxf(fmaxf(m_arr[0], m_arr[1]),
                             fmaxf(m_arr[2], m_arr[3]));
      float sb = 0.f;
#pragma unroll
      for (int c = 0; c < 4; ++c) sb += s_arr[c] * __expf(m_arr[c] - mb);
      float* st = ws + WS_ST + (b * 8 + chunk) * 2;
      st[0] = mb;
      st[1] = sb;
    }
  }
}

// ---------------------------------------------------------------------------
// k2_combine: per b: global (m, S) from 8 chunk stats; weights from raw
// energies; ctx = sum_c exp(m_c - m) * partial_c / S (fixed order). 64 blocks.
// ---------------------------------------------------------------------------
__global__ __launch_bounds__(256) void k2_combine(const float* __restrict__ ws,
                                                  float* __restrict__ wts,
                                                  float* __restrict__ ctx) {
  const int b = blockIdx.x;
  const int tid = threadIdx.x;

  const float* st = ws + WS_ST + b * 16;
  float mb = -3.4e38f;
#pragma unroll
  for (int c = 0; c < 8; ++c) mb = fmaxf(mb, st[2 * c]);
  float S = 0.f;
#pragma unroll
  for (int c = 0; c < 8; ++c) S += st[2 * c + 1] * __expf(st[2 * c] - mb);
  const float inv = 1.f / S;

  __shared__ float esc[8];
  if (tid < 8) esc[tid] = __expf(st[2 * tid] - mb) * inv;
  __syncthreads();

  // weights: 2048 per b
  const float4* en4 = (const float4*)(ws + WS_EN + (size_t)b * TT);
  float4* w4 = (float4*)(wts + (size_t)b * TT);
#pragma unroll
  for (int j = 0; j < 2; ++j) {
    const float4 e = en4[tid * 2 + j];
    float4 w;
    w.x = __expf(e.x - mb) * inv;
    w.y = __expf(e.y - mb) * inv;
    w.z = __expf(e.z - mb) * inv;
    w.w = __expf(e.w - mb) * inv;
    w4[tid * 2 + j] = w;
  }

  // ctx: 512 per b; thread owns float2 column
  const float2* p2 = (const float2*)(ws + WS_PART) + (size_t)b * 8 * 256 + tid;
  float2 s = {0.f, 0.f};
#pragma unroll
  for (int c = 0; c < 8; ++c) {
    const float2 v = p2[c * 256];
    s.x = fmaf(esc[c], v.x, s.x);
    s.y = fmaf(esc[c], v.y, s.y);
  }
  ((float2*)ctx)[b * 256 + tid] = s;
}

// ---------------------------------------------------------------------------
extern "C" void kernel_launch(void* const* d_in, const int* in_sizes, int n_in,
                              void* d_out, int out_size, void* d_ws, size_t ws_size,
                              hipStream_t stream) {
  const float* enc  = (const float*)d_in[0];  // [B,T,E]
  const float* pe   = (const float*)d_in[1];  // [B,T,H]
  const float* lstm = (const float*)d_in[2];  // [B,1,DL]
  const float* awc  = (const float*)d_in[3];  // [B,T]
  const float* Wl   = (const float*)d_in[4];  // [H,DL]
  const float* cw   = (const float*)d_in[5];  // [CC,1,K]
  const float* Wloc = (const float*)d_in[6];  // [H,CC]
  const float* We   = (const float*)d_in[7];  // [1,H]

  float* out = (float*)d_out;
  float* ctx = out;            // [B,E]
  float* wts = out + BB * EE;  // [B,T]
  float* ws = (float*)d_ws;

  k0_prep<<<2049, 256, 0, stream>>>(lstm, Wl, cw, Wloc, ws);
  k1_fused<<<dim3(8, BB), 512, 0, stream>>>(pe, awc, We, enc, ws);
  k2_combine<<<BB, 256, 0, stream>>>(ws, wts, ctx);
}

// Round 13
// 75.987 us; speedup vs baseline: 1.4838x; 1.0303x over previous
//
#include <hip/hip_runtime.h>
#include <math.h>

// Tacotron2 location-sensitive attention, fp32.
// B=64 T=2048 E=512 H=128 DL=1024 CC=32 K=31
// out = [context (B*E=32768), weights (B*T=131072)] fp32, concatenated.
// R13: R12 staggered producer/consumer, refined: 8 sub-tiles x 32 t
// (first flag at ~T_A/8), producer lane = (t, h-half); k2 widened to
// grid (4,64). 3 dispatches, workgroup-scope LDS flags only.

#define BB 64
#define TT 2048
#define EE 512
#define HH 128
#define DLL 1024
#define CCC 32
#define KK 31

// ws layout (in floats)
#define WS_FW   0        // fw[128][32] (col 31 = 0 pad)  -> 4096
#define WS_PL   4096     // pl[64][128]                   -> 8192
#define WS_EN   12288    // energies[64][2048]            -> 131072
#define WS_ST   143360   // stats[64][8][2] (m,s)         -> 1024
#define WS_PART 144384   // partials[64][8][512]          -> 262144

// ---------------------------------------------------------------------------
// k0: blocks 0..2047: one wave per (b,h) dot  pl[b][h] = lstm[b]·W_lstm[h]
//     block 2048: fw[h][k] = sum_c W_loc[h][c]*conv_w[c][k]
// ---------------------------------------------------------------------------
__global__ __launch_bounds__(256) void k0_prep(const float* __restrict__ lstm,
                                               const float* __restrict__ Wl,
                                               const float* __restrict__ cw,
                                               const float* __restrict__ Wloc,
                                               float* __restrict__ ws) {
  const int blk = blockIdx.x;
  const int tid = threadIdx.x;
  if (blk < 2048) {
    const int wave = tid >> 6, lane = tid & 63;
    const int wg = blk * 4 + wave;      // 0..8191
    const int b = wg >> 7, h = wg & 127;
    const float4* wr = (const float4*)(Wl + (size_t)h * DLL);
    const float4* lr = (const float4*)(lstm + (size_t)b * DLL);
    float s = 0.f;
#pragma unroll
    for (int m = 0; m < 4; ++m) {
      float4 a = wr[m * 64 + lane];
      float4 c = lr[m * 64 + lane];
      s += a.x * c.x + a.y * c.y + a.z * c.z + a.w * c.w;
    }
#pragma unroll
    for (int m = 1; m < 64; m <<= 1) s += __shfl_xor(s, m, 64);
    if (lane == 0) ws[WS_PL + b * HH + h] = s;
  } else {
    __shared__ __align__(16) float wl_s[HH * CCC];  // 4096
    __shared__ __align__(16) float cw_s[CCC * KK];  // 992
#pragma unroll
    for (int m = 0; m < 4; ++m)
      ((float4*)wl_s)[tid + 256 * m] = ((const float4*)Wloc)[tid + 256 * m];
    if (tid < 248) ((float4*)cw_s)[tid] = ((const float4*)cw)[tid];
    __syncthreads();
    const int h = tid >> 1;
    const int kbase = (tid & 1) * 16;
    const int kn = (tid & 1) ? 15 : 16;
    for (int kk = 0; kk < kn; ++kk) {
      const int k = kbase + kk;
      float s = 0.f;
#pragma unroll
      for (int c = 0; c < CCC; ++c) s += wl_s[h * CCC + c] * cw_s[c * KK + k];
      ws[WS_FW + h * 32 + k] = s;
    }
    if (tid & 1) ws[WS_FW + h * 32 + 31] = 0.f;  // pad
  }
}

// ---------------------------------------------------------------------------
// k1_fused: grid (8,64), 512 threads. Chunk = 256 t = 8 sub-tiles x 32 t.
// Producers (waves 0-3): wave w covers h in [32w,32w+32); lane = (h-half,
// t): lanes 0-31 do 16 low h, lanes 32-63 do 16 high h for t = sub*32 +
// (lane&31). Sub-tiles swept IN ORDER; pp[sub][w][lane] partials; last
// arriver (LDS counter) combines fixed-order -> energies, stats, flag.
// Consumers (waves 4-7): per sub: acquire, online rescale, stream 32 rows.
// ---------------------------------------------------------------------------
__global__ __launch_bounds__(512, 4) void k1_fused(const float* __restrict__ pe,
                                                   const float* __restrict__ aw,
                                                   const float* __restrict__ We,
                                                   const float* __restrict__ enc,
                                                   float* __restrict__ ws) {
  const int b = blockIdx.y;
  const int chunk = blockIdx.x;      // 0..7
  const int t0 = chunk * 256;
  const int tid = threadIdx.x;
  const int wave = tid >> 6, lane = tid & 63;

  __shared__ __align__(16) float fw_s[HH * 32];   // 16 KB
  __shared__ __align__(16) float aw_s[288];       // halo window
  __shared__ float pl_s[128];
  __shared__ float we_s[128];
  __shared__ __align__(16) float pp[8][4][64];    // partials [sub][wave][lane]
  __shared__ float w_s[256];                      // exp(e - m_sub)
  __shared__ __align__(16) float4 acc_s[128];     // consumer parity combine
  __shared__ float m_arr[8], s_arr[8];
  __shared__ int flag_s[8], cnt_s[8];

  // cooperative staging (all 512 threads)
  {
    const float4* src = (const float4*)(ws + WS_FW);
    float4* dst = (float4*)fw_s;
    dst[tid] = src[tid];
    dst[tid + 512] = src[tid + 512];
  }
  if (tid < 288) {
    const int tg = t0 - 16 + tid;
    aw_s[tid] = (tg >= 0 && tg < TT) ? aw[b * TT + tg] : 0.f;
  }
  if (tid < 128) {
    pl_s[tid] = ws[WS_PL + b * HH + tid];
    we_s[tid] = We[tid];
  }
  if (tid < 8) { flag_s[tid] = 0; cnt_s[tid] = 0; }
  __syncthreads();

  if (wave < 4) {
    // ------- producers: wave w -> h in [32w,32w+32); 8 subs in order -------
    const int th = lane >> 5;            // h-half
    const int lt32 = lane & 31;          // t within sub
    const int hb = wave * 32 + th * 16;  // 16 h from here
#pragma unroll 1
    for (int sub = 0; sub < 8; ++sub) {
      const int lt = sub * 32 + lt32;    // local t 0..255
      float wreg[32];
#pragma unroll
      for (int k = 0; k < 32; ++k) wreg[k] = aw_s[lt + 1 + k];
      const float4* pr4 =
          (const float4*)(pe + ((size_t)b * TT + t0 + lt) * HH) + (hb >> 2);
      float4 ptv[4];
#pragma unroll
      for (int i = 0; i < 4; ++i) ptv[i] = pr4[i];
      float pts[16];
#pragma unroll
      for (int i = 0; i < 4; ++i) {
        pts[4 * i + 0] = ptv[i].x; pts[4 * i + 1] = ptv[i].y;
        pts[4 * i + 2] = ptv[i].z; pts[4 * i + 3] = ptv[i].w;
      }
      float partial = 0.f;
#pragma unroll 2
      for (int hh = 0; hh < 16; ++hh) {
        const int h = hb + hh;
        const float4* fr = (const float4*)&fw_s[h * 32];  // broadcast
        float a0 = pl_s[h] + pts[hh];
        float a1 = 0.f;
#pragma unroll
        for (int q = 0; q < 8; ++q) {
          const float4 f = fr[q];
          a0 = fmaf(f.x, wreg[4 * q + 0], a0);
          a1 = fmaf(f.y, wreg[4 * q + 1], a1);
          a0 = fmaf(f.z, wreg[4 * q + 2], a0);
          a1 = fmaf(f.w, wreg[4 * q + 3], a1);  // q=7: f.w = 0 pad
        }
        const float x = a0 + a1;
        const float thv = 1.f - 2.f / (__expf(2.f * x) + 1.f);
        partial = fmaf(we_s[h], thv, partial);
      }
      pp[sub][wave][lane] = partial;

      int old = 0;
      if (lane == 0)
        old = __hip_atomic_fetch_add(&cnt_s[sub], 1, __ATOMIC_ACQ_REL,
                                     __HIP_MEMORY_SCOPE_WORKGROUP);
      old = __shfl(old, 0, 64);
      if (old == 3) {
        // last arriver: fixed-order combine (8 terms) -> deterministic
        const int lt2 = lane & 31;
        float e = 0.f;
#pragma unroll
        for (int w2 = 0; w2 < 4; ++w2)
          e += pp[sub][w2][lt2] + pp[sub][w2][lt2 + 32];
        if (lane < 32) ws[WS_EN + b * TT + t0 + sub * 32 + lane] = e;
        float m = e;  // duplicated across halves -> max unaffected
#pragma unroll
        for (int s = 1; s < 64; s <<= 1) m = fmaxf(m, __shfl_xor(m, s, 64));
        const float ex = __expf(e - m);
        float p = (lane < 32) ? ex : 0.f;
#pragma unroll
        for (int s = 1; s < 64; s <<= 1) p += __shfl_xor(p, s, 64);
        if (lane < 32) w_s[sub * 32 + lane] = ex;
        if (lane == 0) { m_arr[sub] = m; s_arr[sub] = p; }
        __hip_atomic_store(&flag_s[sub], 1, __ATOMIC_RELEASE,
                           __HIP_MEMORY_SCOPE_WORKGROUP);
      }
    }
    __syncthreads();  // join consumers' barrier
  } else {
    // ---------------- consumers ----------------
    const int cid = tid - 256;     // 0..255
    const int c4 = cid & 127;      // float4 column
    const int tp = cid >> 7;       // parity (wave-uniform)
    const float4* enc4 = (const float4*)(enc + ((size_t)b * TT + t0) * EE);
    float4 a0 = {0.f, 0.f, 0.f, 0.f}, a1 = {0.f, 0.f, 0.f, 0.f};
    float mrun = -3.4e38f;
#pragma unroll 1
    for (int sub = 0; sub < 8; ++sub) {
      while (!__hip_atomic_load(&flag_s[sub], __ATOMIC_ACQUIRE,
                                __HIP_MEMORY_SCOPE_WORKGROUP))
        __builtin_amdgcn_s_sleep(2);
      const float mi = m_arr[sub];
      const float mnew = fmaxf(mrun, mi);
      const float so = __expf(mrun - mnew);  // 0 on first sub
      const float sc = __expf(mi - mnew);
      a0.x *= so; a0.y *= so; a0.z *= so; a0.w *= so;
      a1.x *= so; a1.y *= so; a1.z *= so; a1.w *= so;
      const float* wp = &w_s[sub * 32];
#pragma unroll 8
      for (int i = 0; i < 16; ++i) {
        const int t = 2 * i + tp;
        const float w = wp[t] * sc;
        const float4 v = enc4[(size_t)(sub * 32 + t) * 128 + c4];
        if (i & 1) {
          a1.x = fmaf(w, v.x, a1.x); a1.y = fmaf(w, v.y, a1.y);
          a1.z = fmaf(w, v.z, a1.z); a1.w = fmaf(w, v.w, a1.w);
        } else {
          a0.x = fmaf(w, v.x, a0.x); a0.y = fmaf(w, v.y, a0.y);
          a0.z = fmaf(w, v.z, a0.z); a0.w = fmaf(w, v.w, a0.w);
        }
      }
      mrun = mnew;
    }
    a0.x += a1.x; a0.y += a1.y; a0.z += a1.z; a0.w += a1.w;
    if (tp == 1) acc_s[c4] = a0;      // acc scaled to block max already
    __syncthreads();
    if (tp == 0) {
      const float4 o = acc_s[c4];
      a0.x += o.x; a0.y += o.y; a0.z += o.z; a0.w += o.w;
      ((float4*)(ws + WS_PART))[(size_t)(b * 8 + chunk) * 128 + c4] = a0;
    }
    if (cid == 0) {
      float mb = -3.4e38f;
#pragma unroll
      for (int c = 0; c < 8; ++c) mb = fmaxf(mb, m_arr[c]);
      float sb = 0.f;
#pragma unroll
      for (int c = 0; c < 8; ++c) sb += s_arr[c] * __expf(m_arr[c] - mb);
      float* st = ws + WS_ST + (b * 8 + chunk) * 2;
      st[0] = mb;
      st[1] = sb;
    }
  }
}

// ---------------------------------------------------------------------------
// k2_combine: grid (4,64). Per (quarter q, b): global (m,S) from 8 chunk
// stats; weights for t in [q*512,q*512+512); ctx for float2 cols
// [q*64, q*64+64) = sum_c exp(m_c - m) * partial_c / S (fixed order).
// ---------------------------------------------------------------------------
__global__ __launch_bounds__(256) void k2_combine(const float* __restrict__ ws,
                                                  float* __restrict__ wts,
                                                  float* __restrict__ ctx) {
  const int q = blockIdx.x;   // 0..3
  const int b = blockIdx.y;
  const int tid = threadIdx.x;

  const float* st = ws + WS_ST + b * 16;
  float mb = -3.4e38f;
#pragma unroll
  for (int c = 0; c < 8; ++c) mb = fmaxf(mb, st[2 * c]);
  float S = 0.f;
#pragma unroll
  for (int c = 0; c < 8; ++c) S += st[2 * c + 1] * __expf(st[2 * c] - mb);
  const float inv = 1.f / S;

  // weights: 512 t per block (128 float4)
  {
    const float4* en4 = (const float4*)(ws + WS_EN + (size_t)b * TT) + q * 128;
    float4* w4 = (float4*)(wts + (size_t)b * TT) + q * 128;
    if (tid < 128) {
      const float4 e = en4[tid];
      float4 w;
      w.x = __expf(e.x - mb) * inv;
      w.y = __expf(e.y - mb) * inv;
      w.z = __expf(e.z - mb) * inv;
      w.w = __expf(e.w - mb) * inv;
      w4[tid] = w;
    }
  }

  // ctx: float2 cols [q*64, q*64+64)
  if (tid < 64) {
    const int col = q * 64 + tid;
    const float2* p2 = (const float2*)(ws + WS_PART) + (size_t)b * 8 * 256 + col;
    float2 s = {0.f, 0.f};
#pragma unroll
    for (int c = 0; c < 8; ++c) {
      const float2 v = p2[c * 256];
      const float es = __expf(st[2 * c] - mb) * inv;
      s.x = fmaf(es, v.x, s.x);
      s.y = fmaf(es, v.y, s.y);
    }
    ((float2*)ctx)[b * 256 + col] = s;
  }
}

// ---------------------------------------------------------------------------
extern "C" void kernel_launch(void* const* d_in, const int* in_sizes, int n_in,
                              void* d_out, int out_size, void* d_ws, size_t ws_size,
                              hipStream_t stream) {
  const float* enc  = (const float*)d_in[0];  // [B,T,E]
  const float* pe   = (const float*)d_in[1];  // [B,T,H]
  const float* lstm = (const float*)d_in[2];  // [B,1,DL]
  const float* awc  = (const float*)d_in[3];  // [B,T]
  const float* Wl   = (const float*)d_in[4];  // [H,DL]
  const float* cw   = (const float*)d_in[5];  // [CC,1,K]
  const float* Wloc = (const float*)d_in[6];  // [H,CC]
  const float* We   = (const float*)d_in[7];  // [1,H]

  float* out = (float*)d_out;
  float* ctx = out;            // [B,E]
  float* wts = out + BB * EE;  // [B,T]
  float* ws = (float*)d_ws;

  k0_prep<<<2049, 256, 0, stream>>>(lstm, Wl, cw, Wloc, ws);
  k1_fused<<<dim3(8, BB), 512, 0, stream>>>(pe, awc, We, enc, ws);
  k2_combine<<<dim3(4, BB), 256, 0, stream>>>(ws, wts, ctx);
}